// Round 11
// baseline (57.806 us; speedup 1.0000x reference)
//
#include <hip/hip_runtime.h>
#include <hip/hip_bf16.h>

#define CC 256
#define CMM 32
#define KW 7
#define KK 49
#define PADW 3
#define HH 56
#define WW 56
#define HP 62
#define LP 3844   // 62*62
#define LL 3136   // 56*56
#define BB 2
#define MM 8
#define MIDW 16

typedef __attribute__((ext_vector_type(8))) short bf16x8;
typedef __attribute__((ext_vector_type(4))) float f32x4;
typedef __attribute__((ext_vector_type(8))) unsigned short us8_t;
typedef __attribute__((ext_vector_type(4))) unsigned short us4_t;

__device__ inline short bfr(float f) {   // f32 -> bf16 bits, RNE
  unsigned int u = __builtin_bit_cast(unsigned int, f);
  u += 0x7fffu + ((u >> 16) & 1u);
  return (short)(u >> 16);
}

// ---------------- k/q 1x1 conv over the PADDED 62x62 grid ----------------
// Block = 64 padded-pixels x 4 channel-slices (256 threads); LDS reduce.
// All 64 x-values preloaded into registers (deep ILP), then 16x64 FMA burst.
__global__ void __launch_bounds__(256) kq_kernel(
    const float* __restrict__ x,
    const float* __restrict__ k_w, const float* __restrict__ k_b,
    const float* __restrict__ q_w, const float* __restrict__ q_b,
    float* __restrict__ km, float* __restrict__ qm) {
  __shared__ float red[4][64][17];
  int tid = threadIdx.x;
  int pixi = tid & 63;
  int slice = tid >> 6;
  int p = blockIdx.x * 64 + pixi;
  int g = blockIdx.y;                       // 4 groups of 16 outputs
  int b = blockIdx.z;
  bool valid = (p < LP);
  int py = valid ? p / HP : 0, px = valid ? p % HP : 0;
  bool inb = valid && (py >= PADW && py < PADW + HH && px >= PADW && px < PADW + WW);
  int xo = (py - PADW) * WW + (px - PADW);
  const float* xb = x + (size_t)b * CC * LL + (inb ? xo : 0);
  const float* w0 = (g < 2) ? (k_w + (g * 16) * CC) : (q_w + (g * 16 - CMM) * CC);
  int c0 = slice * 64;

  // 64 outstanding coalesced loads
  float xv[64];
  #pragma unroll
  for (int v = 0; v < 64; ++v)
    xv[v] = inb ? xb[(size_t)(c0 + v) * LL] : 0.f;

  // 1024-FMA burst; weights are lane-uniform s_loads, prefetched across u
  float acc[16];
  #pragma unroll
  for (int u = 0; u < 16; ++u) {
    const float* wr = w0 + u * CC + c0;
    float a = 0.f;
    #pragma unroll
    for (int v = 0; v < 64; ++v)
      a = fmaf(wr[v], xv[v], a);
    acc[u] = a;
  }

  #pragma unroll
  for (int u = 0; u < 16; ++u) red[slice][pixi][u] = acc[u];
  __syncthreads();
  if (slice == 0 && valid) {
    #pragma unroll
    for (int u = 0; u < 16; ++u) {
      float s = red[0][pixi][u] + red[1][pixi][u] + red[2][pixi][u] + red[3][pixi][u];
      int idx = g * 16 + u;
      if (idx < CMM) km[((size_t)b * CMM + idx) * LP + p] = s + k_b[idx];
      else           qm[((size_t)b * CMM + (idx - CMM)) * LP + p] = s + q_b[idx - CMM];
    }
  }
}

// ---------------- fused QK * rowwise-softmax * PV, LDS scalar layout --------
// (identical to R10)
__global__ void __launch_bounds__(512) attn_kernel(
    const float* __restrict__ x, const float* __restrict__ km,
    const float* __restrict__ qm,
    const float* __restrict__ gp_w1, const float* __restrict__ gp_b1,
    const float* __restrict__ gp_w2, const float* __restrict__ gp_b2,
    __hip_bfloat16* __restrict__ pre) {
  __shared__ float xs[MM][10][64];
  __shared__ float ks[10][64];
  __shared__ float gs[KK];
  int t = threadIdx.x;
  int cm = blockIdx.y;
  int b = blockIdx.z;
  int y0 = blockIdx.x * 4;

  if (t < KK) {
    int i = t / KW, j = t % KW;
    float xpos = (float)(j - PADW), ypos = (float)(PADW - i);
    float a = gp_b2[cm];
    #pragma unroll
    for (int m = 0; m < MIDW; ++m) {
      float h = fmaxf(gp_w1[2 * m] * xpos + gp_w1[2 * m + 1] * ypos + gp_b1[m], 0.f);
      a = fmaf(gp_w2[cm * MIDW + m], h, a);
    }
    gs[t] = a;
  }
  const float* kmb = km + ((size_t)b * CMM + cm) * LP;
  for (int e = t; e < 640; e += 512) {
    int ri = e >> 6, cl = e & 63;
    ks[ri][cl] = (cl < HP) ? kmb[(y0 + ri) * HP + cl] : 0.f;
  }
  const float* xg = x + (size_t)b * CC * LL;
  for (int e = t; e < 640; e += 512) {
    int ri = e >> 6, cl = e & 63;
    int ir = y0 - PADW + ri;
    int ic = cl - PADW;
    bool ok = (ir >= 0 && ir < HH && ic >= 0 && ic < WW);
    int off = ok ? (ir * WW + ic) : 0;
    #pragma unroll
    for (int m = 0; m < MM; ++m)
      xs[m][ri][cl] = ok ? xg[(size_t)(m * CMM + cm) * LL + off] : 0.f;
  }
  __syncthreads();

  int w = t >> 6, lane = t & 63;
  int wr = w & 3;                       // row within band
  int mb = (w >> 2) * 4;                // m base: 0 or 4
  int y = y0 + wr;
  int c = lane;
  int ce = (c < WW) ? c : (WW - 1);
  bool act = (c < WW);
  float qc = qm[((size_t)b * CMM + cm) * LP + (y + PADW) * HP + ce + PADW];

  float acc[4] = {0.f, 0.f, 0.f, 0.f};
  #pragma unroll
  for (int i = 0; i < KW; ++i) {
    int row = wr + i;                   // 0..9
    float s[KW];
    #pragma unroll
    for (int j = 0; j < KW; ++j)
      s[j] = fmaf(ks[row][ce + j], qc, gs[i * KW + j]);
    float mx = fmaxf(fmaxf(fmaxf(s[0], s[1]), fmaxf(s[2], s[3])),
                     fmaxf(fmaxf(s[4], s[5]), s[6]));
    float sum = 0.f;
    #pragma unroll
    for (int j = 0; j < KW; ++j) { s[j] = __expf(s[j] - mx); sum += s[j]; }
    float inv = __builtin_amdgcn_rcpf(sum);
    #pragma unroll
    for (int mm = 0; mm < 4; ++mm) {
      const float* xr = &xs[mb + mm][row][ce];
      float dot = s[0] * xr[0];
      dot = fmaf(s[1], xr[1], dot);
      dot = fmaf(s[2], xr[2], dot);
      dot = fmaf(s[3], xr[3], dot);
      dot = fmaf(s[4], xr[4], dot);
      dot = fmaf(s[5], xr[5], dot);
      dot = fmaf(s[6], xr[6], dot);
      acc[mm] = fmaf(dot, inv, acc[mm]);
    }
  }
  if (act) {
    #pragma unroll
    for (int mm = 0; mm < 4; ++mm)
      pre[((size_t)b * CC + ((mb + mm) * CMM + cm)) * LL + y * WW + c] =
          __float2bfloat16(acc[mm]);
  }
}

// ---------------- final 1x1 conv: bf16 MFMA, B staged via LDS ----------------
// (identical to R10)
__global__ void __launch_bounds__(256) fconv_kernel(
    const unsigned short* __restrict__ preb,
    const float* __restrict__ f_w, const float* __restrict__ f_b,
    float* __restrict__ out) {
  __shared__ unsigned short bs[2][32][66];
  int t = threadIdx.x;
  int lane = t & 63;
  int w = t >> 6;
  int px0 = blockIdx.x * 64;
  int oc0 = blockIdx.y * 64;
  int b = blockIdx.z;
  int l15 = lane & 15;
  int hi = lane >> 4;

  bf16x8 af[8];
  const float* wrow = f_w + (size_t)(oc0 + w * 16 + l15) * CC + hi * 8;
  #pragma unroll
  for (int s = 0; s < 8; ++s) {
    f32x4 w0 = *(const f32x4*)(wrow + s * 32);
    f32x4 w1 = *(const f32x4*)(wrow + s * 32 + 4);
    bf16x8 a;
    #pragma unroll
    for (int j = 0; j < 4; ++j) { a[j] = bfr(w0[j]); a[j + 4] = bfr(w1[j]); }
    af[s] = a;
  }

  int srow = t >> 3;
  int scol = (t & 7) * 8;
  const unsigned short* pg = preb + (size_t)b * CC * LL + px0 + scol;

  {
    us8_t v = *(const us8_t*)(pg + (size_t)srow * LL);
    *(us4_t*)&bs[0][srow][scol]     = us4_t{v[0], v[1], v[2], v[3]};
    *(us4_t*)&bs[0][srow][scol + 4] = us4_t{v[4], v[5], v[6], v[7]};
  }

  f32x4 acc[4];
  #pragma unroll
  for (int q = 0; q < 4; ++q) acc[q] = {0.f, 0.f, 0.f, 0.f};

  for (int s = 0; s < 8; ++s) {
    __syncthreads();
    us8_t vnext;
    if (s < 7)
      vnext = *(const us8_t*)(pg + (size_t)((s + 1) * 32 + srow) * LL);
    int cur = s & 1;
    #pragma unroll
    for (int q = 0; q < 4; ++q) {
      bf16x8 bv;
      #pragma unroll
      for (int j = 0; j < 8; ++j)
        bv[j] = (short)bs[cur][hi * 8 + j][q * 16 + l15];
      acc[q] = __builtin_amdgcn_mfma_f32_16x16x32_bf16(af[s], bv, acc[q], 0, 0, 0);
    }
    if (s < 7) {
      *(us4_t*)&bs[cur ^ 1][srow][scol]     = us4_t{vnext[0], vnext[1], vnext[2], vnext[3]};
      *(us4_t*)&bs[cur ^ 1][srow][scol + 4] = us4_t{vnext[4], vnext[5], vnext[6], vnext[7]};
    }
  }

  #pragma unroll
  for (int q = 0; q < 4; ++q) {
    #pragma unroll
    for (int rr = 0; rr < 4; ++rr) {
      int oc = oc0 + w * 16 + hi * 4 + rr;
      out[((size_t)b * CC + oc) * LL + px0 + q * 16 + l15] = acc[q][rr] + f_b[oc];
    }
  }
}

extern "C" void kernel_launch(void* const* d_in, const int* in_sizes, int n_in,
                              void* d_out, int out_size, void* d_ws, size_t ws_size,
                              hipStream_t stream) {
  const float* x     = (const float*)d_in[0];
  const float* k_w   = (const float*)d_in[1];
  const float* k_b   = (const float*)d_in[2];
  const float* q_w   = (const float*)d_in[3];
  const float* q_b   = (const float*)d_in[4];
  const float* gp_w1 = (const float*)d_in[5];
  const float* gp_b1 = (const float*)d_in[6];
  const float* gp_w2 = (const float*)d_in[7];
  const float* gp_b2 = (const float*)d_in[8];
  const float* f_w   = (const float*)d_in[9];
  const float* f_b   = (const float*)d_in[10];
  float* out = (float*)d_out;

  float* ws  = (float*)d_ws;
  float* km  = ws;                                   // 2*32*3844 f32
  float* qm  = km + (size_t)BB * CMM * LP;
  unsigned short* pre = (unsigned short*)(qm + (size_t)BB * CMM * LP); // bf16

  hipLaunchKernelGGL(kq_kernel, dim3((LP + 63) / 64, 4, BB), dim3(256), 0, stream,
                     x, k_w, k_b, q_w, q_b, km, qm);
  hipLaunchKernelGGL(attn_kernel, dim3(HH / 4, CMM, BB), dim3(512), 0, stream,
                     x, km, qm, gp_w1, gp_b1, gp_w2, gp_b2,
                     (__hip_bfloat16*)pre);
  hipLaunchKernelGGL(fconv_kernel, dim3(LL / 64, CC / 64, BB), dim3(256), 0, stream,
                     pre, f_w, f_b, out);
}

// Round 12
// 44.317 us; speedup vs baseline: 1.3044x; 1.3044x over previous
//
#include <hip/hip_runtime.h>
#include <hip/hip_bf16.h>

#define CC 256
#define CMM 32
#define KW 7
#define KK 49
#define PADW 3
#define HH 56
#define WW 56
#define HP 62
#define LP 3844   // 62*62
#define LL 3136   // 56*56
#define BB 2
#define MM 8
#define MIDW 16

typedef __attribute__((ext_vector_type(8))) short bf16x8;
typedef __attribute__((ext_vector_type(4))) float f32x4;
typedef __attribute__((ext_vector_type(8))) unsigned short us8_t;
typedef __attribute__((ext_vector_type(4))) unsigned short us4_t;

__device__ inline short bfr(float f) {   // f32 -> bf16 bits, RNE
  unsigned int u = __builtin_bit_cast(unsigned int, f);
  u += 0x7fffu + ((u >> 16) & 1u);
  return (short)(u >> 16);
}
__device__ inline float bf2f(short h) {
  return __builtin_bit_cast(float, ((unsigned int)(unsigned short)h) << 16);
}

// ---------------- k/q 1x1 conv as bf16 MFMA GEMM (fconv structure) ----------
// [64 oc = k_w(32)++q_w(32)] x [256 c] @ bf16(x)[c][px].  Weights hi/lo-split
// (2 MFMA/tile) for near-f32 weight precision. Outputs inner 56x56 maps.
__global__ void __launch_bounds__(256) kq_kernel(
    const float* __restrict__ x,
    const float* __restrict__ k_w, const float* __restrict__ k_b,
    const float* __restrict__ q_w, const float* __restrict__ q_b,
    float* __restrict__ km, float* __restrict__ qm) {
  __shared__ unsigned short bs[2][32][66];
  int t = threadIdx.x;
  int lane = t & 63;
  int w = t >> 6;
  int px0 = blockIdx.x * 64;
  int b = blockIdx.z;
  int l15 = lane & 15;
  int hi = lane >> 4;                 // 0..3 (k-quarter)

  // A-frags hi/lo: oc = w*16 + l15; k = s*32 + hi*8 + j
  int oc_a = w * 16 + l15;
  const float* wrow = ((oc_a < CMM) ? (k_w + (size_t)oc_a * CC)
                                    : (q_w + (size_t)(oc_a - CMM) * CC)) + hi * 8;
  bf16x8 ah[8], al[8];
  #pragma unroll
  for (int s = 0; s < 8; ++s) {
    f32x4 w0 = *(const f32x4*)(wrow + s * 32);
    f32x4 w1 = *(const f32x4*)(wrow + s * 32 + 4);
    bf16x8 h, l;
    #pragma unroll
    for (int j = 0; j < 4; ++j) {
      short hb0 = bfr(w0[j]); h[j] = hb0;     l[j] = bfr(w0[j] - bf2f(hb0));
      short hb1 = bfr(w1[j]); h[j + 4] = hb1; l[j + 4] = bfr(w1[j] - bf2f(hb1));
    }
    ah[s] = h; al[s] = l;
  }

  int srow = t >> 3;                  // c within chunk (0..31)
  int scol = (t & 7) * 8;             // px offset (0..56)
  const float* xg = x + (size_t)b * CC * LL + px0 + scol;

  // prologue: stage chunk 0
  {
    f32x4 v0 = *(const f32x4*)(xg + (size_t)srow * LL);
    f32x4 v1 = *(const f32x4*)(xg + (size_t)srow * LL + 4);
    us4_t h0, h1;
    #pragma unroll
    for (int j = 0; j < 4; ++j) { h0[j] = (unsigned short)bfr(v0[j]); h1[j] = (unsigned short)bfr(v1[j]); }
    *(us4_t*)&bs[0][srow][scol]     = h0;
    *(us4_t*)&bs[0][srow][scol + 4] = h1;
  }

  f32x4 acc[4];
  #pragma unroll
  for (int q = 0; q < 4; ++q) acc[q] = {0.f, 0.f, 0.f, 0.f};

  for (int s = 0; s < 8; ++s) {
    __syncthreads();
    f32x4 v0, v1;
    if (s < 7) {
      v0 = *(const f32x4*)(xg + (size_t)((s + 1) * 32 + srow) * LL);
      v1 = *(const f32x4*)(xg + (size_t)((s + 1) * 32 + srow) * LL + 4);
    }
    int cur = s & 1;
    #pragma unroll
    for (int q = 0; q < 4; ++q) {
      bf16x8 bv;
      #pragma unroll
      for (int j = 0; j < 8; ++j)
        bv[j] = (short)bs[cur][hi * 8 + j][q * 16 + l15];
      acc[q] = __builtin_amdgcn_mfma_f32_16x16x32_bf16(ah[s], bv, acc[q], 0, 0, 0);
      acc[q] = __builtin_amdgcn_mfma_f32_16x16x32_bf16(al[s], bv, acc[q], 0, 0, 0);
    }
    if (s < 7) {
      us4_t h0, h1;
      #pragma unroll
      for (int j = 0; j < 4; ++j) { h0[j] = (unsigned short)bfr(v0[j]); h1[j] = (unsigned short)bfr(v1[j]); }
      *(us4_t*)&bs[cur ^ 1][srow][scol]     = h0;
      *(us4_t*)&bs[cur ^ 1][srow][scol + 4] = h1;
    }
  }

  #pragma unroll
  for (int q = 0; q < 4; ++q) {
    #pragma unroll
    for (int rr = 0; rr < 4; ++rr) {
      int oc = w * 16 + hi * 4 + rr;
      int px = px0 + q * 16 + l15;
      if (oc < CMM)
        km[((size_t)b * CMM + oc) * LL + px] = acc[q][rr] + k_b[oc];
      else
        qm[((size_t)b * CMM + (oc - CMM)) * LL + px] = acc[q][rr] + q_b[oc - CMM];
    }
  }
}

// ---------------- fused QK * rowwise-softmax * PV, LDS scalar layout --------
// (R10 structure; km/qm now inner-56x56, border km synthesized as k_b[cm])
__global__ void __launch_bounds__(512) attn_kernel(
    const float* __restrict__ x, const float* __restrict__ km,
    const float* __restrict__ qm,
    const float* __restrict__ gp_w1, const float* __restrict__ gp_b1,
    const float* __restrict__ gp_w2, const float* __restrict__ gp_b2,
    const float* __restrict__ k_b,
    __hip_bfloat16* __restrict__ pre) {
  __shared__ float xs[MM][10][64];
  __shared__ float ks[10][64];
  __shared__ float gs[KK];
  int t = threadIdx.x;
  int cm = blockIdx.y;
  int b = blockIdx.z;
  int y0 = blockIdx.x * 4;

  if (t < KK) {
    int i = t / KW, j = t % KW;
    float xpos = (float)(j - PADW), ypos = (float)(PADW - i);
    float a = gp_b2[cm];
    #pragma unroll
    for (int m = 0; m < MIDW; ++m) {
      float h = fmaxf(gp_w1[2 * m] * xpos + gp_w1[2 * m + 1] * ypos + gp_b1[m], 0.f);
      a = fmaf(gp_w2[cm * MIDW + m], h, a);
    }
    gs[t] = a;
  }
  float kb_cm = k_b[cm];
  const float* kmb = km + ((size_t)b * CMM + cm) * LL;
  for (int e = t; e < 640; e += 512) {
    int ri = e >> 6, cl = e & 63;
    int rp = y0 + ri;                     // padded row
    bool inner = (rp >= PADW && rp < PADW + HH && cl >= PADW && cl < PADW + WW);
    ks[ri][cl] = inner ? kmb[(rp - PADW) * WW + (cl - PADW)] : kb_cm;
  }
  const float* xg = x + (size_t)b * CC * LL;
  for (int e = t; e < 640; e += 512) {
    int ri = e >> 6, cl = e & 63;
    int ir = y0 - PADW + ri;
    int ic = cl - PADW;
    bool ok = (ir >= 0 && ir < HH && ic >= 0 && ic < WW);
    int off = ok ? (ir * WW + ic) : 0;
    #pragma unroll
    for (int m = 0; m < MM; ++m)
      xs[m][ri][cl] = ok ? xg[(size_t)(m * CMM + cm) * LL + off] : 0.f;
  }
  __syncthreads();

  int w = t >> 6, lane = t & 63;
  int wr = w & 3;                       // row within band
  int mb = (w >> 2) * 4;                // m base: 0 or 4
  int y = y0 + wr;
  int c = lane;
  int ce = (c < WW) ? c : (WW - 1);
  bool act = (c < WW);
  float qc = qm[((size_t)b * CMM + cm) * LL + y * WW + ce];

  float acc[4] = {0.f, 0.f, 0.f, 0.f};
  #pragma unroll
  for (int i = 0; i < KW; ++i) {
    int row = wr + i;                   // 0..9
    float s[KW];
    #pragma unroll
    for (int j = 0; j < KW; ++j)
      s[j] = fmaf(ks[row][ce + j], qc, gs[i * KW + j]);
    float mx = fmaxf(fmaxf(fmaxf(s[0], s[1]), fmaxf(s[2], s[3])),
                     fmaxf(fmaxf(s[4], s[5]), s[6]));
    float sum = 0.f;
    #pragma unroll
    for (int j = 0; j < KW; ++j) { s[j] = __expf(s[j] - mx); sum += s[j]; }
    float inv = __builtin_amdgcn_rcpf(sum);
    #pragma unroll
    for (int mm = 0; mm < 4; ++mm) {
      const float* xr = &xs[mb + mm][row][ce];
      float dot = s[0] * xr[0];
      dot = fmaf(s[1], xr[1], dot);
      dot = fmaf(s[2], xr[2], dot);
      dot = fmaf(s[3], xr[3], dot);
      dot = fmaf(s[4], xr[4], dot);
      dot = fmaf(s[5], xr[5], dot);
      dot = fmaf(s[6], xr[6], dot);
      acc[mm] = fmaf(dot, inv, acc[mm]);
    }
  }
  if (act) {
    #pragma unroll
    for (int mm = 0; mm < 4; ++mm)
      pre[((size_t)b * CC + ((mb + mm) * CMM + cm)) * LL + y * WW + c] =
          __float2bfloat16(acc[mm]);
  }
}

// ---------------- final 1x1 conv: bf16 MFMA, B staged via LDS ----------------
// (identical to R10)
__global__ void __launch_bounds__(256) fconv_kernel(
    const unsigned short* __restrict__ preb,
    const float* __restrict__ f_w, const float* __restrict__ f_b,
    float* __restrict__ out) {
  __shared__ unsigned short bs[2][32][66];
  int t = threadIdx.x;
  int lane = t & 63;
  int w = t >> 6;
  int px0 = blockIdx.x * 64;
  int oc0 = blockIdx.y * 64;
  int b = blockIdx.z;
  int l15 = lane & 15;
  int hi = lane >> 4;

  bf16x8 af[8];
  const float* wrow = f_w + (size_t)(oc0 + w * 16 + l15) * CC + hi * 8;
  #pragma unroll
  for (int s = 0; s < 8; ++s) {
    f32x4 w0 = *(const f32x4*)(wrow + s * 32);
    f32x4 w1 = *(const f32x4*)(wrow + s * 32 + 4);
    bf16x8 a;
    #pragma unroll
    for (int j = 0; j < 4; ++j) { a[j] = bfr(w0[j]); a[j + 4] = bfr(w1[j]); }
    af[s] = a;
  }

  int srow = t >> 3;
  int scol = (t & 7) * 8;
  const unsigned short* pg = preb + (size_t)b * CC * LL + px0 + scol;

  {
    us8_t v = *(const us8_t*)(pg + (size_t)srow * LL);
    *(us4_t*)&bs[0][srow][scol]     = us4_t{v[0], v[1], v[2], v[3]};
    *(us4_t*)&bs[0][srow][scol + 4] = us4_t{v[4], v[5], v[6], v[7]};
  }

  f32x4 acc[4];
  #pragma unroll
  for (int q = 0; q < 4; ++q) acc[q] = {0.f, 0.f, 0.f, 0.f};

  for (int s = 0; s < 8; ++s) {
    __syncthreads();
    us8_t vnext;
    if (s < 7)
      vnext = *(const us8_t*)(pg + (size_t)((s + 1) * 32 + srow) * LL);
    int cur = s & 1;
    #pragma unroll
    for (int q = 0; q < 4; ++q) {
      bf16x8 bv;
      #pragma unroll
      for (int j = 0; j < 8; ++j)
        bv[j] = (short)bs[cur][hi * 8 + j][q * 16 + l15];
      acc[q] = __builtin_amdgcn_mfma_f32_16x16x32_bf16(af[s], bv, acc[q], 0, 0, 0);
    }
    if (s < 7) {
      *(us4_t*)&bs[cur ^ 1][srow][scol]     = us4_t{vnext[0], vnext[1], vnext[2], vnext[3]};
      *(us4_t*)&bs[cur ^ 1][srow][scol + 4] = us4_t{vnext[4], vnext[5], vnext[6], vnext[7]};
    }
  }

  #pragma unroll
  for (int q = 0; q < 4; ++q) {
    #pragma unroll
    for (int rr = 0; rr < 4; ++rr) {
      int oc = oc0 + w * 16 + hi * 4 + rr;
      out[((size_t)b * CC + oc) * LL + px0 + q * 16 + l15] = acc[q][rr] + f_b[oc];
    }
  }
}

extern "C" void kernel_launch(void* const* d_in, const int* in_sizes, int n_in,
                              void* d_out, int out_size, void* d_ws, size_t ws_size,
                              hipStream_t stream) {
  const float* x     = (const float*)d_in[0];
  const float* k_w   = (const float*)d_in[1];
  const float* k_b   = (const float*)d_in[2];
  const float* q_w   = (const float*)d_in[3];
  const float* q_b   = (const float*)d_in[4];
  const float* gp_w1 = (const float*)d_in[5];
  const float* gp_b1 = (const float*)d_in[6];
  const float* gp_w2 = (const float*)d_in[7];
  const float* gp_b2 = (const float*)d_in[8];
  const float* f_w   = (const float*)d_in[9];
  const float* f_b   = (const float*)d_in[10];
  float* out = (float*)d_out;

  float* ws  = (float*)d_ws;
  float* km  = ws;                                   // 2*32*3136 f32 (inner)
  float* qm  = km + (size_t)BB * CMM * LL;
  unsigned short* pre = (unsigned short*)(qm + (size_t)BB * CMM * LL); // bf16

  hipLaunchKernelGGL(kq_kernel, dim3(LL / 64, 1, BB), dim3(256), 0, stream,
                     x, k_w, k_b, q_w, q_b, km, qm);
  hipLaunchKernelGGL(attn_kernel, dim3(HH / 4, CMM, BB), dim3(512), 0, stream,
                     x, km, qm, gp_w1, gp_b1, gp_w2, gp_b2, k_b,
                     (__hip_bfloat16*)pre);
  hipLaunchKernelGGL(fconv_kernel, dim3(LL / 64, CC / 64, BB), dim3(256), 0, stream,
                     pre, f_w, f_b, out);
}